// Round 5
// baseline (177.255 us; speedup 1.0000x reference)
//
#include <hip/hip_runtime.h>
#include <math.h>

#define BB 2
#define NN 2048
#define EE 256
#define HH 8
#define DD 32

typedef __attribute__((ext_vector_type(8))) short short8;
typedef __attribute__((ext_vector_type(4))) short short4v;
typedef __attribute__((ext_vector_type(4))) float f32x4;

union VU { short8 v; short4v h[2]; };

__device__ inline unsigned short f2bf(float f) {
  union { float f; unsigned int u; } a; a.f = f;
  unsigned int r = a.u + 0x7FFFu + ((a.u >> 16) & 1u);
  return (unsigned short)(r >> 16);
}

// ---------------------------------------------------------------------------
// QKV projection GEMM: qkvb[row][col] = bf16(A@W^T + b), also V^T per head:
// vt[(b*8+h)*32+d][n].  A:(4096x256) f32, W:(768x256) f32.
// ---------------------------------------------------------------------------
__global__ __launch_bounds__(256) void gemm_qkv_kernel(const float* __restrict__ A,
                                                       const float* __restrict__ W,
                                                       const float* __restrict__ bias,
                                                       unsigned short* __restrict__ qkvb,
                                                       unsigned short* __restrict__ vt) {
  __shared__ float As[64][17];
  __shared__ float Ws[64][17];
  int tid = threadIdx.x;
  int tx = tid & 15, ty = tid >> 4;
  int rowBase = blockIdx.y * 64;
  int colBase = blockIdx.x * 64;
  float acc[4][4] = {};
  for (int k0 = 0; k0 < EE; k0 += 16) {
#pragma unroll
    for (int t = 0; t < 4; ++t) {
      int idx = tid + t * 256;
      int r = idx >> 4, c = idx & 15;
      As[r][c] = A[(size_t)(rowBase + r) * EE + k0 + c];
      Ws[r][c] = W[(size_t)(colBase + r) * EE + k0 + c];
    }
    __syncthreads();
#pragma unroll
    for (int kk = 0; kk < 16; ++kk) {
      float a[4], w[4];
#pragma unroll
      for (int i = 0; i < 4; ++i) a[i] = As[ty * 4 + i][kk];
#pragma unroll
      for (int j = 0; j < 4; ++j) w[j] = Ws[tx * 4 + j][kk];
#pragma unroll
      for (int i = 0; i < 4; ++i)
#pragma unroll
        for (int j = 0; j < 4; ++j)
          acc[i][j] = fmaf(a[i], w[j], acc[i][j]);
    }
    __syncthreads();
  }
  unsigned short bv[4][4];
#pragma unroll
  for (int i = 0; i < 4; ++i)
#pragma unroll
    for (int j = 0; j < 4; ++j)
      bv[i][j] = f2bf(acc[i][j] + bias[colBase + tx * 4 + j]);

#pragma unroll
  for (int i = 0; i < 4; ++i) {
    int row = rowBase + ty * 4 + i;
    ushort4 u;
    u.x = bv[i][0]; u.y = bv[i][1]; u.z = bv[i][2]; u.w = bv[i][3];
    *(ushort4*)(qkvb + (size_t)row * 768 + colBase + tx * 4) = u;
  }
  if (colBase >= 512) {
    int rowb = rowBase + ty * 4;
    int b = rowb >> 11, n = rowb & 2047;
#pragma unroll
    for (int j = 0; j < 4; ++j) {
      int hd = colBase + tx * 4 + j - 512;
      ushort4 u;
      u.x = bv[0][j]; u.y = bv[1][j]; u.z = bv[2][j]; u.w = bv[3][j];
      *(ushort4*)(vt + ((size_t)(b * 8 + (hd >> 5)) * 32 + (hd & 31)) * NN + n) = u;
    }
  }
}

// ---------------------------------------------------------------------------
// tau2[row][h] = (dot(feat,tau_w[h]) + tau_b[h]) * log2e;  cxy[row] = centers
// ---------------------------------------------------------------------------
__global__ __launch_bounds__(256) void tau_cxy_kernel(const float* __restrict__ feat,
                                                      const float* __restrict__ tau_w,
                                                      const float* __restrict__ tau_b,
                                                      const float* __restrict__ bbox,
                                                      float* __restrict__ tau2,
                                                      float2* __restrict__ cxy) {
  int idx = blockIdx.x * 256 + threadIdx.x;
  int row = idx >> 3, h = idx & 7;
  const float4* f = (const float4*)(feat + (size_t)row * EE);
  const float4* w = (const float4*)(tau_w + (size_t)h * EE);
  float s = 0.f;
#pragma unroll 8
  for (int e = 0; e < EE / 4; ++e) {
    float4 a = f[e], b4 = w[e];
    s = fmaf(a.x, b4.x, s);
    s = fmaf(a.y, b4.y, s);
    s = fmaf(a.z, b4.z, s);
    s = fmaf(a.w, b4.w, s);
  }
  tau2[idx] = (s + tau_b[h]) * 1.4426950408889634f;
  if (h == 0) {
    float2 c;
    c.x = bbox[(size_t)row * 4 + 0];
    c.y = bbox[(size_t)row * 4 + 1];
    cxy[row] = c;
  }
}

// ---------------------------------------------------------------------------
// MFMA flash attention, 4-wave K-split, ROUND-3 NUMERICS (online max per
// wave) + m-aware LDS merge. grid = (B*H, N/16); block = 256 (4 waves).
// Wave w handles keys [w*512, w*512+512) in 8 tiles of 64; K-frags
// register-double-buffered. Merge: M=max_w m_w; scale_w=2^(m_w-M);
// O = sum_w acc_w*scale_w / sum_w l_w*scale_w.
// ---------------------------------------------------------------------------
__global__ __launch_bounds__(256) void attn_kernel(const unsigned short* __restrict__ qkvb,
                                                   const unsigned short* __restrict__ vt,
                                                   const float2* __restrict__ cxy,
                                                   const float* __restrict__ tau2,
                                                   float* __restrict__ o_out) {
  __shared__ float accT[4][32][17];
  __shared__ float mT[4][16];
  __shared__ float lT[4][16];
  __shared__ float sT[4][16];
  __shared__ float linv[16];

  int bh = blockIdx.x;
  int b = bh >> 3, h = bh & 7;
  int qt = blockIdx.y;
  int tid = threadIdx.x;
  int w = tid >> 6;
  int lane = tid & 63;
  int q15 = lane & 15, g = lane >> 4;
  int rowq = b * NN + qt * 16 + q15;

  short8 qf = *(const short8*)(qkvb + (size_t)rowq * 768 + h * 32 + g * 8);
  float2 ci = cxy[rowq];
  float t2 = tau2[(size_t)rowq * HH + h];
  const float rs2 = 0.17677669529663687f * 1.4426950408889634f;  // 1/sqrt(32)*log2e

  float m = -INFINITY, l = 0.f;
  f32x4 acc0 = {0.f, 0.f, 0.f, 0.f}, acc1 = {0.f, 0.f, 0.f, 0.f};

  const unsigned short* kp = qkvb + (size_t)b * NN * 768 + 256 + h * 32 + (size_t)q15 * 768 + g * 8;
  const unsigned short* vbase = vt + (size_t)bh * 32 * NN;
  const float2* cb = cxy + b * NN;

  int j0base = w * 512;

  short8 kf[2][4];
  VU vf[2][2];

#pragma unroll
  for (int t = 0; t < 4; ++t)
    kf[0][t] = *(const short8*)(kp + (size_t)(j0base + t * 16) * 768);

#pragma unroll
  for (int tt = 0; tt < 8; ++tt) {
    const int cur = tt & 1, nxt = cur ^ 1;
    const int j0 = j0base + tt * 64;
    if (tt < 7) {
#pragma unroll
      for (int t = 0; t < 4; ++t)
        kf[nxt][t] = *(const short8*)(kp + (size_t)(j0 + 64 + t * 16) * 768);
    }
#pragma unroll
    for (int t2i = 0; t2i < 2; ++t2i)
#pragma unroll
      for (int dh = 0; dh < 2; ++dh) {
        const unsigned short* vr = vbase + (size_t)(dh * 16 + q15) * NN + j0 + t2i * 32 + g * 4;
        vf[t2i][dh].h[0] = *(const short4v*)(vr);
        vf[t2i][dh].h[1] = *(const short4v*)(vr + 16);
      }
    // ---- S^T tiles: 4x mfma (A = K rows, B = Q) ----
    f32x4 st[4];
#pragma unroll
    for (int t = 0; t < 4; ++t)
      st[t] = __builtin_amdgcn_mfma_f32_16x16x32_bf16(kf[cur][t], qf, (f32x4){0.f, 0.f, 0.f, 0.f}, 0, 0, 0);
    // ---- mask + online softmax (round-3 numerics) ----
    float s[16];
    float tmax = -INFINITY;
#pragma unroll
    for (int t = 0; t < 4; ++t) {
      float4 c01 = *(const float4*)(cb + j0 + t * 16 + g * 4);
      float4 c23 = *(const float4*)(cb + j0 + t * 16 + g * 4 + 2);
      float cx[4] = {c01.x, c01.z, c23.x, c23.z};
      float cy[4] = {c01.y, c01.w, c23.y, c23.w};
#pragma unroll
      for (int r = 0; r < 4; ++r) {
        float dx = ci.x - cx[r], dy = ci.y - cy[r];
        float dist = __builtin_amdgcn_sqrtf(fmaf(dy, dy, dx * dx));
        float e = fmaf(st[t][r], rs2, -dist * t2);
        s[t * 4 + r] = e;
        tmax = fmaxf(tmax, e);
      }
    }
    tmax = fmaxf(tmax, __shfl_xor(tmax, 16));
    tmax = fmaxf(tmax, __shfl_xor(tmax, 32));
    float mn = fmaxf(m, tmax);
    float scale = __builtin_amdgcn_exp2f(m - mn);
    m = mn;
    float p[16], lsum = 0.f;
#pragma unroll
    for (int i = 0; i < 16; ++i) {
      p[i] = __builtin_amdgcn_exp2f(s[i] - mn);
      lsum += p[i];
    }
    l = fmaf(l, scale, lsum);
#pragma unroll
    for (int r = 0; r < 4; ++r) { acc0[r] *= scale; acc1[r] *= scale; }
    // ---- pack P to bf16 B-frags ----
    union { short8 v; unsigned int u[4]; } pf[2];
#pragma unroll
    for (int t2i = 0; t2i < 2; ++t2i)
#pragma unroll
      for (int wq = 0; wq < 4; ++wq) {
        float lo = p[(t2i * 2 + (wq >> 1)) * 4 + (wq & 1) * 2];
        float hi = p[(t2i * 2 + (wq >> 1)) * 4 + (wq & 1) * 2 + 1];
        asm("v_cvt_pk_bf16_f32 %0, %1, %2" : "=v"(pf[t2i].u[wq]) : "v"(lo), "v"(hi));
      }
    // ---- PV: 4x mfma, acc in O^T layout (col=q, row=d) ----
    acc0 = __builtin_amdgcn_mfma_f32_16x16x32_bf16(vf[0][0].v, pf[0].v, acc0, 0, 0, 0);
    acc1 = __builtin_amdgcn_mfma_f32_16x16x32_bf16(vf[0][1].v, pf[0].v, acc1, 0, 0, 0);
    acc0 = __builtin_amdgcn_mfma_f32_16x16x32_bf16(vf[1][0].v, pf[1].v, acc0, 0, 0, 0);
    acc1 = __builtin_amdgcn_mfma_f32_16x16x32_bf16(vf[1][1].v, pf[1].v, acc1, 0, 0, 0);
  }

  // wave-level l reduce across the 4 g-groups (acc holds full key-sum per d,q)
  l += __shfl_xor(l, 16);
  l += __shfl_xor(l, 32);

  // ---- store per-wave partials ----
#pragma unroll
  for (int r = 0; r < 4; ++r) {
    accT[w][g * 4 + r][q15] = acc0[r];
    accT[w][16 + g * 4 + r][q15] = acc1[r];
  }
  if (g == 0) {
    mT[w][q15] = m;
    lT[w][q15] = l;
  }
  __syncthreads();

  // ---- m-aware merge of the 4 wave-partials ----
  if (tid < 16) {
    float M = mT[0][tid];
#pragma unroll
    for (int ww = 1; ww < 4; ++ww) M = fmaxf(M, mT[ww][tid]);
    float L = 0.f;
#pragma unroll
    for (int ww = 0; ww < 4; ++ww) {
      float sc = __builtin_amdgcn_exp2f(mT[ww][tid] - M);
      sT[ww][tid] = sc;
      L += lT[ww][tid] * sc;
    }
    linv[tid] = 1.f / L;
  }
  __syncthreads();

#pragma unroll
  for (int ii = 0; ii < 2; ++ii) {
    int i = tid + ii * 256;
    int q = i >> 5, d = i & 31;
    float ov = (accT[0][d][q] * sT[0][q] + accT[1][d][q] * sT[1][q] +
                accT[2][d][q] * sT[2][q] + accT[3][d][q] * sT[3][q]) * linv[q];
    o_out[((size_t)b * NN + qt * 16 + q) * EE + h * 32 + d] = ov;
  }
}

// ---------------------------------------------------------------------------
// Out projection (fp32): C = A@W^T + b + resid
// ---------------------------------------------------------------------------
__global__ __launch_bounds__(256) void gemm_out_kernel(const float* __restrict__ A,
                                                       const float* __restrict__ W,
                                                       const float* __restrict__ bias,
                                                       const float* __restrict__ resid,
                                                       float* __restrict__ C) {
  __shared__ float As[64][17];
  __shared__ float Ws[64][17];
  int tid = threadIdx.x;
  int tx = tid & 15, ty = tid >> 4;
  int rowBase = blockIdx.y * 64;
  int colBase = blockIdx.x * 64;
  float acc[4][4] = {};
  for (int k0 = 0; k0 < EE; k0 += 16) {
#pragma unroll
    for (int t = 0; t < 4; ++t) {
      int idx = tid + t * 256;
      int r = idx >> 4, c = idx & 15;
      As[r][c] = A[(size_t)(rowBase + r) * EE + k0 + c];
      Ws[r][c] = W[(size_t)(colBase + r) * EE + k0 + c];
    }
    __syncthreads();
#pragma unroll
    for (int kk = 0; kk < 16; ++kk) {
      float a[4], w[4];
#pragma unroll
      for (int i = 0; i < 4; ++i) a[i] = As[ty * 4 + i][kk];
#pragma unroll
      for (int j = 0; j < 4; ++j) w[j] = Ws[tx * 4 + j][kk];
#pragma unroll
      for (int i = 0; i < 4; ++i)
#pragma unroll
        for (int j = 0; j < 4; ++j)
          acc[i][j] = fmaf(a[i], w[j], acc[i][j]);
    }
    __syncthreads();
  }
#pragma unroll
  for (int i = 0; i < 4; ++i) {
    int row = rowBase + ty * 4 + i;
#pragma unroll
    for (int j = 0; j < 4; ++j) {
      int col = colBase + tx * 4 + j;
      float v = acc[i][j] + bias[col] + resid[(size_t)row * EE + col];
      C[(size_t)row * EE + col] = v;
    }
  }
}

extern "C" void kernel_launch(void* const* d_in, const int* in_sizes, int n_in,
                              void* d_out, int out_size, void* d_ws, size_t ws_size,
                              hipStream_t stream) {
  const float* bbox  = (const float*)d_in[0];
  const float* feat  = (const float*)d_in[1];
  const float* in_w  = (const float*)d_in[2];
  const float* in_b  = (const float*)d_in[3];
  const float* out_w = (const float*)d_in[4];
  const float* out_b = (const float*)d_in[5];
  const float* tau_w = (const float*)d_in[6];
  const float* tau_b = (const float*)d_in[7];
  float* out = (float*)d_out;

  float* o = (float*)d_ws;                                   // 1,048,576 f32
  unsigned short* qkvb = (unsigned short*)(o + 1048576);     // 3,145,728 bf16
  unsigned short* vt = qkvb + 3145728;                       // 1,048,576 bf16
  float* tau2 = (float*)(vt + 1048576);                      // 32,768 f32
  float2* cxy = (float2*)(tau2 + 32768);                     // 4,096 float2

  gemm_qkv_kernel<<<dim3(12, 64), 256, 0, stream>>>(feat, in_w, in_b, qkvb, vt);
  tau_cxy_kernel<<<dim3(128), 256, 0, stream>>>(feat, tau_w, tau_b, bbox, tau2, cxy);
  attn_kernel<<<dim3(BB * HH, NN / 16), 256, 0, stream>>>(qkvb, vt, cxy, tau2, o);
  gemm_out_kernel<<<dim3(EE / 64, (BB * NN) / 64), 256, 0, stream>>>(o, out_w, out_b, feat, out);
}

// Round 6
// 122.757 us; speedup vs baseline: 1.4439x; 1.4439x over previous
//
#include <hip/hip_runtime.h>
#include <math.h>

#define BB 2
#define NN 2048
#define EE 256
#define HH 8
#define DD 32

typedef __attribute__((ext_vector_type(8))) short short8;
typedef __attribute__((ext_vector_type(4))) float f32x4;

__device__ inline unsigned short f2bf(float f) {
  union { float f; unsigned int u; } a; a.f = f;
  unsigned int r = a.u + 0x7FFFu + ((a.u >> 16) & 1u);
  return (unsigned short)(r >> 16);
}

// ---------------------------------------------------------------------------
// QKV projection GEMM. Outputs (all bf16):
//   qb [row][256]                Q, row-major
//   kh [bh][n][32]               K contiguous per head (frag loads = 1KB blocks)
//   vpi[bh][n>>5][32][32]        V^T in 32-key chunks, key-interleaved cols:
//                                c' = ((k&15)<<1)|(k>>4)  (pairs (k,k+16) adjacent)
// ---------------------------------------------------------------------------
__global__ __launch_bounds__(256) void gemm_qkv_kernel(const float* __restrict__ A,
                                                       const float* __restrict__ W,
                                                       const float* __restrict__ bias,
                                                       unsigned short* __restrict__ qb,
                                                       unsigned short* __restrict__ kh,
                                                       unsigned short* __restrict__ vpi) {
  __shared__ float As[64][17];
  __shared__ float Ws[64][17];
  int tid = threadIdx.x;
  int tx = tid & 15, ty = tid >> 4;
  int rowBase = blockIdx.y * 64;
  int colBase = blockIdx.x * 64;
  float acc[4][4] = {};
  for (int k0 = 0; k0 < EE; k0 += 16) {
#pragma unroll
    for (int t = 0; t < 4; ++t) {
      int idx = tid + t * 256;
      int r = idx >> 4, c = idx & 15;
      As[r][c] = A[(size_t)(rowBase + r) * EE + k0 + c];
      Ws[r][c] = W[(size_t)(colBase + r) * EE + k0 + c];
    }
    __syncthreads();
#pragma unroll
    for (int kk = 0; kk < 16; ++kk) {
      float a[4], w[4];
#pragma unroll
      for (int i = 0; i < 4; ++i) a[i] = As[ty * 4 + i][kk];
#pragma unroll
      for (int j = 0; j < 4; ++j) w[j] = Ws[tx * 4 + j][kk];
#pragma unroll
      for (int i = 0; i < 4; ++i)
#pragma unroll
        for (int j = 0; j < 4; ++j)
          acc[i][j] = fmaf(a[i], w[j], acc[i][j]);
    }
    __syncthreads();
  }
  unsigned short bv[4][4];
#pragma unroll
  for (int i = 0; i < 4; ++i)
#pragma unroll
    for (int j = 0; j < 4; ++j)
      bv[i][j] = f2bf(acc[i][j] + bias[colBase + tx * 4 + j]);

  if (colBase < 256) {
    // ---- Q third ----
#pragma unroll
    for (int i = 0; i < 4; ++i) {
      int row = rowBase + ty * 4 + i;
      ushort4 u;
      u.x = bv[i][0]; u.y = bv[i][1]; u.z = bv[i][2]; u.w = bv[i][3];
      *(ushort4*)(qb + (size_t)row * 256 + colBase + tx * 4) = u;
    }
  } else if (colBase < 512) {
    // ---- K third -> kh[bh][n][32] ----
    int hd = colBase - 256 + tx * 4;
    int h = hd >> 5, d = hd & 31;
#pragma unroll
    for (int i = 0; i < 4; ++i) {
      int row = rowBase + ty * 4 + i;
      int b = row >> 11, n = row & 2047;
      ushort4 u;
      u.x = bv[i][0]; u.y = bv[i][1]; u.z = bv[i][2]; u.w = bv[i][3];
      *(ushort4*)(kh + ((size_t)(b * 8 + h) * NN + n) * 32 + d) = u;
    }
  } else {
    // ---- V third -> vpi, interleaved scatter (2B stores) ----
#pragma unroll
    for (int j = 0; j < 4; ++j) {
      int hd = colBase - 512 + tx * 4 + j;
      int h = hd >> 5, d = hd & 31;
#pragma unroll
      for (int i = 0; i < 4; ++i) {
        int row = rowBase + ty * 4 + i;
        int b = row >> 11, n = row & 2047;
        int chunk = n >> 5, klo = n & 31;
        int cp = ((klo & 15) << 1) | (klo >> 4);
        vpi[(((size_t)(b * 8 + h) * 64 + chunk) * 32 + d) * 32 + cp] = bv[i][j];
      }
    }
  }
}

// ---------------------------------------------------------------------------
// tau2[row][h] = (dot(feat,tau_w[h]) + tau_b[h]) * log2e;  cxy[row] = centers
// ---------------------------------------------------------------------------
__global__ __launch_bounds__(256) void tau_cxy_kernel(const float* __restrict__ feat,
                                                      const float* __restrict__ tau_w,
                                                      const float* __restrict__ tau_b,
                                                      const float* __restrict__ bbox,
                                                      float* __restrict__ tau2,
                                                      float2* __restrict__ cxy) {
  int idx = blockIdx.x * 256 + threadIdx.x;
  int row = idx >> 3, h = idx & 7;
  const float4* f = (const float4*)(feat + (size_t)row * EE);
  const float4* w = (const float4*)(tau_w + (size_t)h * EE);
  float s = 0.f;
#pragma unroll 8
  for (int e = 0; e < EE / 4; ++e) {
    float4 a = f[e], b4 = w[e];
    s = fmaf(a.x, b4.x, s);
    s = fmaf(a.y, b4.y, s);
    s = fmaf(a.z, b4.z, s);
    s = fmaf(a.w, b4.w, s);
  }
  tau2[idx] = (s + tau_b[h]) * 1.4426950408889634f;
  if (h == 0) {
    float2 c;
    c.x = bbox[(size_t)row * 4 + 0];
    c.y = bbox[(size_t)row * 4 + 1];
    cxy[row] = c;
  }
}

// ---------------------------------------------------------------------------
// MFMA flash attention, 4-wave K-split, online-max numerics + m-aware merge.
// All K/V fragment loads are CONTIGUOUS 1KB-per-instruction (kh / vpi
// layouts), fixing the L1 scattered-line bottleneck of rounds 3-5.
// ---------------------------------------------------------------------------
__global__ __launch_bounds__(256) void attn_kernel(const unsigned short* __restrict__ qb,
                                                   const unsigned short* __restrict__ kh,
                                                   const unsigned short* __restrict__ vpi,
                                                   const float2* __restrict__ cxy,
                                                   const float* __restrict__ tau2,
                                                   float* __restrict__ o_out) {
  __shared__ float accT[4][32][17];
  __shared__ float mT[4][16];
  __shared__ float lT[4][16];
  __shared__ float sT[4][16];
  __shared__ float linv[16];

  int bh = blockIdx.x;
  int b = bh >> 3, h = bh & 7;
  int qt = blockIdx.y;
  int tid = threadIdx.x;
  int w = tid >> 6;
  int lane = tid & 63;
  int q15 = lane & 15, g = lane >> 4;
  int rowq = b * NN + qt * 16 + q15;

  short8 qf = *(const short8*)(qb + (size_t)rowq * 256 + h * 32 + g * 8);
  float2 ci = cxy[rowq];
  float t2 = tau2[(size_t)rowq * HH + h];
  const float rs2 = 0.17677669529663687f * 1.4426950408889634f;  // 1/sqrt(32)*log2e

  float m = -INFINITY, l = 0.f;
  f32x4 acc0 = {0.f, 0.f, 0.f, 0.f}, acc1 = {0.f, 0.f, 0.f, 0.f};

  // per-lane base pointers (contiguous-frag layouts)
  const unsigned short* kb = kh + (size_t)bh * NN * 32 + q15 * 32 + g * 8;
  const unsigned short* vb = vpi + (size_t)bh * NN * 32 + q15 * 32 + g * 8;
  const float2* cb = cxy + b * NN;

  int j0base = w * 512;

  short8 kf[2][4];
  short8 vf[2][2];

#pragma unroll
  for (int t = 0; t < 4; ++t)
    kf[0][t] = *(const short8*)(kb + (size_t)(j0base + t * 16) * 32);

#pragma unroll
  for (int tt = 0; tt < 8; ++tt) {
    const int cur = tt & 1, nxt = cur ^ 1;
    const int j0 = j0base + tt * 64;
    // prefetch next tile's K-frags (1KB contiguous per inst)
    if (tt < 7) {
#pragma unroll
      for (int t = 0; t < 4; ++t)
        kf[nxt][t] = *(const short8*)(kb + (size_t)(j0 + 64 + t * 16) * 32);
    }
    // V frags: contiguous 16B/lane; [t2i][dh] = 32-key chunk, d-half
#pragma unroll
    for (int t2i = 0; t2i < 2; ++t2i)
#pragma unroll
      for (int dh = 0; dh < 2; ++dh)
        vf[t2i][dh] = *(const short8*)(vb + (size_t)((j0 >> 5) + t2i) * 1024 + dh * 512);
    // ---- S^T tiles: 4x mfma (A = K rows, B = Q) ----
    f32x4 st[4];
#pragma unroll
    for (int t = 0; t < 4; ++t)
      st[t] = __builtin_amdgcn_mfma_f32_16x16x32_bf16(kf[cur][t], qf, (f32x4){0.f, 0.f, 0.f, 0.f}, 0, 0, 0);
    // ---- mask + online softmax ----
    float s[16];
    float tmax = -INFINITY;
#pragma unroll
    for (int t = 0; t < 4; ++t) {
      float4 c01 = *(const float4*)(cb + j0 + t * 16 + g * 4);
      float4 c23 = *(const float4*)(cb + j0 + t * 16 + g * 4 + 2);
      float cx[4] = {c01.x, c01.z, c23.x, c23.z};
      float cy[4] = {c01.y, c01.w, c23.y, c23.w};
#pragma unroll
      for (int r = 0; r < 4; ++r) {
        float dx = ci.x - cx[r], dy = ci.y - cy[r];
        float dist = __builtin_amdgcn_sqrtf(fmaf(dy, dy, dx * dx));
        float e = fmaf(st[t][r], rs2, -dist * t2);
        s[t * 4 + r] = e;
        tmax = fmaxf(tmax, e);
      }
    }
    tmax = fmaxf(tmax, __shfl_xor(tmax, 16));
    tmax = fmaxf(tmax, __shfl_xor(tmax, 32));
    float mn = fmaxf(m, tmax);
    float scale = __builtin_amdgcn_exp2f(m - mn);
    m = mn;
    float p[16], lsum = 0.f;
#pragma unroll
    for (int i = 0; i < 16; ++i) {
      p[i] = __builtin_amdgcn_exp2f(s[i] - mn);
      lsum += p[i];
    }
    l = fmaf(l, scale, lsum);
#pragma unroll
    for (int r = 0; r < 4; ++r) { acc0[r] *= scale; acc1[r] *= scale; }
    // ---- pack P to bf16 B-frags: u[w] pairs keys (k, k+16) ----
    union { short8 v; unsigned int u[4]; } pf[2];
#pragma unroll
    for (int t2i = 0; t2i < 2; ++t2i)
#pragma unroll
      for (int wq = 0; wq < 4; ++wq) {
        float lo = p[t2i * 8 + wq];
        float hi = p[t2i * 8 + 4 + wq];
        asm("v_cvt_pk_bf16_f32 %0, %1, %2" : "=v"(pf[t2i].u[wq]) : "v"(lo), "v"(hi));
      }
    // ---- PV: 4x mfma, acc in O^T layout (col=q, row=d) ----
    acc0 = __builtin_amdgcn_mfma_f32_16x16x32_bf16(vf[0][0], pf[0].v, acc0, 0, 0, 0);
    acc1 = __builtin_amdgcn_mfma_f32_16x16x32_bf16(vf[0][1], pf[0].v, acc1, 0, 0, 0);
    acc0 = __builtin_amdgcn_mfma_f32_16x16x32_bf16(vf[1][0], pf[1].v, acc0, 0, 0, 0);
    acc1 = __builtin_amdgcn_mfma_f32_16x16x32_bf16(vf[1][1], pf[1].v, acc1, 0, 0, 0);
  }

  // wave-level l reduce across g-groups (acc holds full key-sum per d,q)
  l += __shfl_xor(l, 16);
  l += __shfl_xor(l, 32);

  // ---- store per-wave partials ----
#pragma unroll
  for (int r = 0; r < 4; ++r) {
    accT[w][g * 4 + r][q15] = acc0[r];
    accT[w][16 + g * 4 + r][q15] = acc1[r];
  }
  if (g == 0) {
    mT[w][q15] = m;
    lT[w][q15] = l;
  }
  __syncthreads();

  // ---- m-aware merge of the 4 wave-partials ----
  if (tid < 16) {
    float M = mT[0][tid];
#pragma unroll
    for (int ww = 1; ww < 4; ++ww) M = fmaxf(M, mT[ww][tid]);
    float L = 0.f;
#pragma unroll
    for (int ww = 0; ww < 4; ++ww) {
      float sc = __builtin_amdgcn_exp2f(mT[ww][tid] - M);
      sT[ww][tid] = sc;
      L += lT[ww][tid] * sc;
    }
    linv[tid] = 1.f / L;
  }
  __syncthreads();

#pragma unroll
  for (int ii = 0; ii < 2; ++ii) {
    int i = tid + ii * 256;
    int q = i >> 5, d = i & 31;
    float ov = (accT[0][d][q] * sT[0][q] + accT[1][d][q] * sT[1][q] +
                accT[2][d][q] * sT[2][q] + accT[3][d][q] * sT[3][q]) * linv[q];
    o_out[((size_t)b * NN + qt * 16 + q) * EE + h * 32 + d] = ov;
  }
}

// ---------------------------------------------------------------------------
// Out projection (fp32): C = A@W^T + b + resid
// ---------------------------------------------------------------------------
__global__ __launch_bounds__(256) void gemm_out_kernel(const float* __restrict__ A,
                                                       const float* __restrict__ W,
                                                       const float* __restrict__ bias,
                                                       const float* __restrict__ resid,
                                                       float* __restrict__ C) {
  __shared__ float As[64][17];
  __shared__ float Ws[64][17];
  int tid = threadIdx.x;
  int tx = tid & 15, ty = tid >> 4;
  int rowBase = blockIdx.y * 64;
  int colBase = blockIdx.x * 64;
  float acc[4][4] = {};
  for (int k0 = 0; k0 < EE; k0 += 16) {
#pragma unroll
    for (int t = 0; t < 4; ++t) {
      int idx = tid + t * 256;
      int r = idx >> 4, c = idx & 15;
      As[r][c] = A[(size_t)(rowBase + r) * EE + k0 + c];
      Ws[r][c] = W[(size_t)(colBase + r) * EE + k0 + c];
    }
    __syncthreads();
#pragma unroll
    for (int kk = 0; kk < 16; ++kk) {
      float a[4], w[4];
#pragma unroll
      for (int i = 0; i < 4; ++i) a[i] = As[ty * 4 + i][kk];
#pragma unroll
      for (int j = 0; j < 4; ++j) w[j] = Ws[tx * 4 + j][kk];
#pragma unroll
      for (int i = 0; i < 4; ++i)
#pragma unroll
        for (int j = 0; j < 4; ++j)
          acc[i][j] = fmaf(a[i], w[j], acc[i][j]);
    }
    __syncthreads();
  }
#pragma unroll
  for (int i = 0; i < 4; ++i) {
    int row = rowBase + ty * 4 + i;
#pragma unroll
    for (int j = 0; j < 4; ++j) {
      int col = colBase + tx * 4 + j;
      float v = acc[i][j] + bias[col] + resid[(size_t)row * EE + col];
      C[(size_t)row * EE + col] = v;
    }
  }
}

extern "C" void kernel_launch(void* const* d_in, const int* in_sizes, int n_in,
                              void* d_out, int out_size, void* d_ws, size_t ws_size,
                              hipStream_t stream) {
  const float* bbox  = (const float*)d_in[0];
  const float* feat  = (const float*)d_in[1];
  const float* in_w  = (const float*)d_in[2];
  const float* in_b  = (const float*)d_in[3];
  const float* out_w = (const float*)d_in[4];
  const float* out_b = (const float*)d_in[5];
  const float* tau_w = (const float*)d_in[6];
  const float* tau_b = (const float*)d_in[7];
  float* out = (float*)d_out;

  float* o = (float*)d_ws;                                 // 1,048,576 f32
  unsigned short* qb  = (unsigned short*)(o + 1048576);    // 1,048,576 bf16
  unsigned short* kh  = qb + 1048576;                      // 1,048,576 bf16
  unsigned short* vpi = kh + 1048576;                      // 1,048,576 bf16
  float* tau2 = (float*)(vpi + 1048576);                   // 32,768 f32
  float2* cxy = (float2*)(tau2 + 32768);                   // 4,096 float2

  gemm_qkv_kernel<<<dim3(12, 64), 256, 0, stream>>>(feat, in_w, in_b, qb, kh, vpi);
  tau_cxy_kernel<<<dim3(128), 256, 0, stream>>>(feat, tau_w, tau_b, bbox, tau2, cxy);
  attn_kernel<<<dim3(BB * HH, NN / 16), 256, 0, stream>>>(qb, kh, vpi, cxy, tau2, o);
  gemm_out_kernel<<<dim3(EE / 64, (BB * NN) / 64), 256, 0, stream>>>(o, out_w, out_b, feat, out);
}

// Round 7
// 97.773 us; speedup vs baseline: 1.8129x; 1.2555x over previous
//
#include <hip/hip_runtime.h>
#include <math.h>

#define BB 2
#define NN 2048
#define EE 256
#define HH 8
#define DD 32

typedef __attribute__((ext_vector_type(8))) short short8;
typedef __attribute__((ext_vector_type(4))) float f32x4;

__device__ inline unsigned short f2bf(float f) {
  union { float f; unsigned int u; } a; a.f = f;
  unsigned int r = a.u + 0x7FFFu + ((a.u >> 16) & 1u);
  return (unsigned short)(r >> 16);
}

// ---------------------------------------------------------------------------
// Cast projection weights to bf16. in_w: 768x256, out_w: 256x256.
// 65536 threads x 4 elems.
// ---------------------------------------------------------------------------
__global__ __launch_bounds__(256) void cast_w_kernel(const float* __restrict__ in_w,
                                                     const float* __restrict__ out_w,
                                                     unsigned short* __restrict__ in_wb,
                                                     unsigned short* __restrict__ out_wb) {
  int i = blockIdx.x * 256 + threadIdx.x;
  float4 v;
  unsigned short* dst;
  if (i < 49152) {
    v = ((const float4*)in_w)[i];
    dst = in_wb + (size_t)i * 4;
  } else {
    v = ((const float4*)out_w)[i - 49152];
    dst = out_wb + (size_t)(i - 49152) * 4;
  }
  ushort4 u;
  u.x = f2bf(v.x); u.y = f2bf(v.y); u.z = f2bf(v.z); u.w = f2bf(v.w);
  *(ushort4*)dst = u;
}

// ---------------------------------------------------------------------------
// tau2[row][h] = (dot(feat,tau_w[h]) + tau_b[h]) * log2e;  cxy = centers;
// also casts feat -> featb (bf16), each thread h covers e in [h*8, h*8+8).
// ---------------------------------------------------------------------------
__global__ __launch_bounds__(256) void tau_cxy_kernel(const float* __restrict__ feat,
                                                      const float* __restrict__ tau_w,
                                                      const float* __restrict__ tau_b,
                                                      const float* __restrict__ bbox,
                                                      float* __restrict__ tau2,
                                                      float2* __restrict__ cxy,
                                                      unsigned short* __restrict__ featb) {
  int idx = blockIdx.x * 256 + threadIdx.x;
  int row = idx >> 3, h = idx & 7;
  const float4* f = (const float4*)(feat + (size_t)row * EE);
  const float4* w = (const float4*)(tau_w + (size_t)h * EE);
  float s = 0.f;
#pragma unroll 8
  for (int e = 0; e < EE / 4; ++e) {
    float4 a = f[e], b4 = w[e];
    s = fmaf(a.x, b4.x, s);
    s = fmaf(a.y, b4.y, s);
    s = fmaf(a.z, b4.z, s);
    s = fmaf(a.w, b4.w, s);
    if ((e >> 3) == h) {
      ushort4 u;
      u.x = f2bf(a.x); u.y = f2bf(a.y); u.z = f2bf(a.z); u.w = f2bf(a.w);
      *(ushort4*)(featb + (size_t)row * EE + e * 4) = u;
    }
  }
  tau2[idx] = (s + tau_b[h]) * 1.4426950408889634f;
  if (h == 0) {
    float2 c;
    c.x = bbox[(size_t)row * 4 + 0];
    c.y = bbox[(size_t)row * 4 + 1];
    cxy[row] = c;
  }
}

// ---------------------------------------------------------------------------
// bf16 MFMA GEMM: C[m,n] = A[m,:] . W[n,:] + bias[n], A: M x 256, W: N x 256.
// Block = 4 waves; tile 64(M) x 64(N); wave = 16 M-rows; no LDS (L1/L2 reuse).
// Frag conventions identical to attn kernel (validated):
//   operand frag: lane(p,g) holds row p, k-slice g*8; result row=g*4+reg (first
//   operand's rows), col=lane&15 (second operand's rows).
// MODE 0: qkv epilogue -> qb/kh/vpi (bf16).  MODE 1: out = v + resid (fp32).
// ---------------------------------------------------------------------------
template <int MODE>
__global__ __launch_bounds__(256) void gemm_mfma_kernel(const unsigned short* __restrict__ Ab,
                                                        const unsigned short* __restrict__ Wb,
                                                        const float* __restrict__ bias,
                                                        const float* __restrict__ resid,
                                                        float* __restrict__ Cf,
                                                        unsigned short* __restrict__ qb,
                                                        unsigned short* __restrict__ kh,
                                                        unsigned short* __restrict__ vpi) {
  int tid = threadIdx.x;
  int wv = tid >> 6, lane = tid & 63;
  int p = lane & 15, g = lane >> 4;
  int mW = blockIdx.y * 64 + wv * 16;
  int nB = blockIdx.x * 64;

  const unsigned short* ap = Ab + (size_t)(mW + p) * 256 + g * 8;
  const unsigned short* wp = Wb + (size_t)(nB + p) * 256 + g * 8;

  f32x4 acc[4] = {{0.f, 0.f, 0.f, 0.f}, {0.f, 0.f, 0.f, 0.f},
                  {0.f, 0.f, 0.f, 0.f}, {0.f, 0.f, 0.f, 0.f}};
#pragma unroll
  for (int kk = 0; kk < 8; ++kk) {
    short8 af = *(const short8*)(ap + kk * 32);
#pragma unroll
    for (int t = 0; t < 4; ++t) {
      short8 wf = *(const short8*)(wp + (size_t)t * 16 * 256 + kk * 32);
      acc[t] = __builtin_amdgcn_mfma_f32_16x16x32_bf16(af, wf, acc[t], 0, 0, 0);
    }
  }

#pragma unroll
  for (int t = 0; t < 4; ++t) {
    int n = nB + t * 16 + p;
    float bn = bias[n];
#pragma unroll
    for (int r = 0; r < 4; ++r) {
      int m = mW + g * 4 + r;
      float v = acc[t][r] + bn;
      if (MODE == 1) {
        Cf[(size_t)m * 256 + n] = v + resid[(size_t)m * 256 + n];
      } else {
        unsigned short bv = f2bf(v);
        int b = m >> 11, tok = m & 2047;
        if (n < 256) {
          qb[(size_t)m * 256 + n] = bv;
        } else if (n < 512) {
          int h = (n - 256) >> 5, d = n & 31;
          kh[((size_t)(b * 8 + h) * NN + tok) * 32 + d] = bv;
        } else {
          int h = (n - 512) >> 5, d = n & 31;
          int cp = ((tok & 15) << 1) | ((tok >> 4) & 1);
          vpi[(((size_t)(b * 8 + h) * 64 + (tok >> 5)) * 32 + d) * 32 + cp] = bv;
        }
      }
    }
  }
}

// ---------------------------------------------------------------------------
// MFMA flash attention (round-6 validated), 4-wave K-split, online-max +
// m-aware merge; contiguous kh/vpi frag layouts. Epilogue now writes o bf16.
// ---------------------------------------------------------------------------
__global__ __launch_bounds__(256) void attn_kernel(const unsigned short* __restrict__ qb,
                                                   const unsigned short* __restrict__ kh,
                                                   const unsigned short* __restrict__ vpi,
                                                   const float2* __restrict__ cxy,
                                                   const float* __restrict__ tau2,
                                                   unsigned short* __restrict__ ob) {
  __shared__ float accT[4][32][17];
  __shared__ float mT[4][16];
  __shared__ float lT[4][16];
  __shared__ float sT[4][16];
  __shared__ float linv[16];

  int bh = blockIdx.x;
  int b = bh >> 3, h = bh & 7;
  int qt = blockIdx.y;
  int tid = threadIdx.x;
  int w = tid >> 6;
  int lane = tid & 63;
  int q15 = lane & 15, g = lane >> 4;
  int rowq = b * NN + qt * 16 + q15;

  short8 qf = *(const short8*)(qb + (size_t)rowq * 256 + h * 32 + g * 8);
  float2 ci = cxy[rowq];
  float t2 = tau2[(size_t)rowq * HH + h];
  const float rs2 = 0.17677669529663687f * 1.4426950408889634f;  // 1/sqrt(32)*log2e

  float m = -INFINITY, l = 0.f;
  f32x4 acc0 = {0.f, 0.f, 0.f, 0.f}, acc1 = {0.f, 0.f, 0.f, 0.f};

  const unsigned short* kb = kh + (size_t)bh * NN * 32 + q15 * 32 + g * 8;
  const unsigned short* vb = vpi + (size_t)bh * NN * 32 + q15 * 32 + g * 8;
  const float2* cb = cxy + b * NN;

  int j0base = w * 512;

  short8 kf[2][4];
  short8 vf[2][2];

#pragma unroll
  for (int t = 0; t < 4; ++t)
    kf[0][t] = *(const short8*)(kb + (size_t)(j0base + t * 16) * 32);

#pragma unroll
  for (int tt = 0; tt < 8; ++tt) {
    const int cur = tt & 1, nxt = cur ^ 1;
    const int j0 = j0base + tt * 64;
    if (tt < 7) {
#pragma unroll
      for (int t = 0; t < 4; ++t)
        kf[nxt][t] = *(const short8*)(kb + (size_t)(j0 + 64 + t * 16) * 32);
    }
#pragma unroll
    for (int t2i = 0; t2i < 2; ++t2i)
#pragma unroll
      for (int dh = 0; dh < 2; ++dh)
        vf[t2i][dh] = *(const short8*)(vb + (size_t)((j0 >> 5) + t2i) * 1024 + dh * 512);
    f32x4 st[4];
#pragma unroll
    for (int t = 0; t < 4; ++t)
      st[t] = __builtin_amdgcn_mfma_f32_16x16x32_bf16(kf[cur][t], qf, (f32x4){0.f, 0.f, 0.f, 0.f}, 0, 0, 0);
    float s[16];
    float tmax = -INFINITY;
#pragma unroll
    for (int t = 0; t < 4; ++t) {
      float4 c01 = *(const float4*)(cb + j0 + t * 16 + g * 4);
      float4 c23 = *(const float4*)(cb + j0 + t * 16 + g * 4 + 2);
      float cx[4] = {c01.x, c01.z, c23.x, c23.z};
      float cy[4] = {c01.y, c01.w, c23.y, c23.w};
#pragma unroll
      for (int r = 0; r < 4; ++r) {
        float dx = ci.x - cx[r], dy = ci.y - cy[r];
        float dist = __builtin_amdgcn_sqrtf(fmaf(dy, dy, dx * dx));
        float e = fmaf(st[t][r], rs2, -dist * t2);
        s[t * 4 + r] = e;
        tmax = fmaxf(tmax, e);
      }
    }
    tmax = fmaxf(tmax, __shfl_xor(tmax, 16));
    tmax = fmaxf(tmax, __shfl_xor(tmax, 32));
    float mn = fmaxf(m, tmax);
    float scale = __builtin_amdgcn_exp2f(m - mn);
    m = mn;
    float p[16], lsum = 0.f;
#pragma unroll
    for (int i = 0; i < 16; ++i) {
      p[i] = __builtin_amdgcn_exp2f(s[i] - mn);
      lsum += p[i];
    }
    l = fmaf(l, scale, lsum);
#pragma unroll
    for (int r = 0; r < 4; ++r) { acc0[r] *= scale; acc1[r] *= scale; }
    union { short8 v; unsigned int u[4]; } pf[2];
#pragma unroll
    for (int t2i = 0; t2i < 2; ++t2i)
#pragma unroll
      for (int wq = 0; wq < 4; ++wq) {
        float lo = p[t2i * 8 + wq];
        float hi = p[t2i * 8 + 4 + wq];
        asm("v_cvt_pk_bf16_f32 %0, %1, %2" : "=v"(pf[t2i].u[wq]) : "v"(lo), "v"(hi));
      }
    acc0 = __builtin_amdgcn_mfma_f32_16x16x32_bf16(vf[0][0], pf[0].v, acc0, 0, 0, 0);
    acc1 = __builtin_amdgcn_mfma_f32_16x16x32_bf16(vf[0][1], pf[0].v, acc1, 0, 0, 0);
    acc0 = __builtin_amdgcn_mfma_f32_16x16x32_bf16(vf[1][0], pf[1].v, acc0, 0, 0, 0);
    acc1 = __builtin_amdgcn_mfma_f32_16x16x32_bf16(vf[1][1], pf[1].v, acc1, 0, 0, 0);
  }

  l += __shfl_xor(l, 16);
  l += __shfl_xor(l, 32);

#pragma unroll
  for (int r = 0; r < 4; ++r) {
    accT[w][g * 4 + r][q15] = acc0[r];
    accT[w][16 + g * 4 + r][q15] = acc1[r];
  }
  if (g == 0) {
    mT[w][q15] = m;
    lT[w][q15] = l;
  }
  __syncthreads();

  if (tid < 16) {
    float M = mT[0][tid];
#pragma unroll
    for (int ww = 1; ww < 4; ++ww) M = fmaxf(M, mT[ww][tid]);
    float L = 0.f;
#pragma unroll
    for (int ww = 0; ww < 4; ++ww) {
      float sc = __builtin_amdgcn_exp2f(mT[ww][tid] - M);
      sT[ww][tid] = sc;
      L += lT[ww][tid] * sc;
    }
    linv[tid] = 1.f / L;
  }
  __syncthreads();

#pragma unroll
  for (int ii = 0; ii < 2; ++ii) {
    int i = tid + ii * 256;
    int q = i >> 5, d = i & 31;
    float ov = (accT[0][d][q] * sT[0][q] + accT[1][d][q] * sT[1][q] +
                accT[2][d][q] * sT[2][q] + accT[3][d][q] * sT[3][q]) * linv[q];
    ob[((size_t)b * NN + qt * 16 + q) * EE + h * 32 + d] = f2bf(ov);
  }
}

extern "C" void kernel_launch(void* const* d_in, const int* in_sizes, int n_in,
                              void* d_out, int out_size, void* d_ws, size_t ws_size,
                              hipStream_t stream) {
  const float* bbox  = (const float*)d_in[0];
  const float* feat  = (const float*)d_in[1];
  const float* in_w  = (const float*)d_in[2];
  const float* in_b  = (const float*)d_in[3];
  const float* out_w = (const float*)d_in[4];
  const float* out_b = (const float*)d_in[5];
  const float* tau_w = (const float*)d_in[6];
  const float* tau_b = (const float*)d_in[7];
  float* out = (float*)d_out;

  unsigned short* ob     = (unsigned short*)d_ws;   // 1M bf16
  unsigned short* featb  = ob + 1048576;            // 1M bf16
  unsigned short* qb     = featb + 1048576;         // 1M bf16
  unsigned short* kh     = qb + 1048576;            // 1M bf16
  unsigned short* vpi    = kh + 1048576;            // 1M bf16
  unsigned short* in_wb  = vpi + 1048576;           // 196608 bf16
  unsigned short* out_wb = in_wb + 196608;          // 65536 bf16
  float* tau2 = (float*)(out_wb + 65536);           // 32768 f32
  float2* cxy = (float2*)(tau2 + 32768);            // 4096 float2

  cast_w_kernel<<<dim3(256), 256, 0, stream>>>(in_w, out_w, in_wb, out_wb);
  tau_cxy_kernel<<<dim3(128), 256, 0, stream>>>(feat, tau_w, tau_b, bbox, tau2, cxy, featb);
  // QKV projection: (4096 x 256) @ (768 x 256)^T
  gemm_mfma_kernel<0><<<dim3(12, 64), 256, 0, stream>>>(featb, in_wb, in_b, nullptr, nullptr,
                                                        qb, kh, vpi);
  attn_kernel<<<dim3(BB * HH, NN / 16), 256, 0, stream>>>(qb, kh, vpi, cxy, tau2, ob);
  // Out projection + bias + residual: (4096 x 256) @ (256 x 256)^T
  gemm_mfma_kernel<1><<<dim3(4, 64), 256, 0, stream>>>(ob, out_wb, out_b, feat, out,
                                                       nullptr, nullptr, nullptr);
}